// Round 1
// baseline (297.594 us; speedup 1.0000x reference)
//
#include <hip/hip_runtime.h>

typedef unsigned short u16;
typedef __bf16 bf16x8 __attribute__((ext_vector_type(8)));
typedef float f32x4 __attribute__((ext_vector_type(4)));

__device__ __forceinline__ u16 f2bf(float f) {
    unsigned u = __builtin_bit_cast(unsigned, f);
    u += 0x7fffu + ((u >> 16) & 1u);
    return (u16)(u >> 16);
}

#define GLDS16(g, l) __builtin_amdgcn_global_load_lds( \
    (const __attribute__((address_space(1))) void*)(g), \
    (__attribute__((address_space(3))) void*)(l), 16, 0, 0)

// ---------------------------------------------------------------------------
// Weight conversion: fp32 -> bf16 (Wq|Wk|Wv stacked, Wp), concat biases.
// ---------------------------------------------------------------------------
__global__ __launch_bounds__(256) void convert_kernel(
    const float* __restrict__ Wq, const float* __restrict__ Wk,
    const float* __restrict__ Wv, const float* __restrict__ Wp,
    const float* __restrict__ bq, const float* __restrict__ bk,
    const float* __restrict__ bv,
    u16* __restrict__ Wqkv, u16* __restrict__ Wpb, float* __restrict__ bqkv)
{
    int idx = blockIdx.x * 256 + threadIdx.x;  // 4096 blocks * 256 = 1048576
    if (idx < 786432) {
        int which = idx >> 18;            // 262144 elems per matrix
        int off   = idx & 262143;
        const float* src = (which == 0) ? Wq : (which == 1) ? Wk : Wv;
        Wqkv[idx] = f2bf(src[off]);
    } else {
        int off = idx - 786432;
        Wpb[off] = f2bf(Wp[off]);
    }
    if (idx < 1536) {
        const float* bsrc = (idx < 512) ? bq : (idx < 1024) ? bk : bv;
        bqkv[idx] = bsrc[idx & 511];
    }
}

// ---------------------------------------------------------------------------
// GroupNorm: x [B,C,T] fp32 -> h_t [B,T,C] bf16.  One block per (b, group).
// Group = 16 channels * 1024 px = one contiguous 16384-float span.
// ---------------------------------------------------------------------------
__global__ __launch_bounds__(256) void gn_kernel(
    const float* __restrict__ x, const float* __restrict__ gamma,
    const float* __restrict__ beta, u16* __restrict__ ht)
{
    const int g = blockIdx.x, b = blockIdx.y, tid = threadIdx.x;
    const float* xg = x + ((size_t)b * 512 + (size_t)g * 16) * 1024;

    float s = 0.f, s2 = 0.f;
    const float4* x4 = (const float4*)xg;
    #pragma unroll 4
    for (int i = tid; i < 4096; i += 256) {
        float4 v = x4[i];
        s  += v.x + v.y + v.z + v.w;
        s2 += v.x * v.x + v.y * v.y + v.z * v.z + v.w * v.w;
    }
    #pragma unroll
    for (int off = 32; off; off >>= 1) {
        s  += __shfl_down(s, off);
        s2 += __shfl_down(s2, off);
    }
    __shared__ float rs[4], rs2[4];
    __shared__ float stat[2];
    const int w = tid >> 6;
    if ((tid & 63) == 0) { rs[w] = s; rs2[w] = s2; }
    __syncthreads();
    if (tid == 0) {
        float S  = rs[0] + rs[1] + rs[2] + rs[3];
        float S2 = rs2[0] + rs2[1] + rs2[2] + rs2[3];
        float mean = S * (1.f / 16384.f);
        float var  = S2 * (1.f / 16384.f) - mean * mean;
        stat[0] = mean;
        stat[1] = rsqrtf(var + 1e-5f);
    }
    __syncthreads();
    const float mean = stat[0], rstd = stat[1];

    float ga[16], be[16];
    #pragma unroll
    for (int ci = 0; ci < 16; ci++) {
        ga[ci] = gamma[g * 16 + ci];
        be[ci] = beta[g * 16 + ci];
    }
    // pass 2: each thread handles one t per iter; writes 16 contiguous bf16
    for (int t = tid; t < 1024; t += 256) {
        u16 yv[16];
        #pragma unroll
        for (int ci = 0; ci < 16; ci++) {
            float v = xg[ci * 1024 + t];
            yv[ci] = f2bf((v - mean) * rstd * ga[ci] + be[ci]);
        }
        uint4* dst = (uint4*)(ht + ((size_t)b * 1024 + t) * 512 + g * 16);
        dst[0] = ((const uint4*)yv)[0];
        dst[1] = ((const uint4*)yv)[1];
    }
}

// ---------------------------------------------------------------------------
// Row softmax over scores [16*1024 rows, 1024 cols] fp32, writes bf16 P
// IN PLACE (row r bf16 occupies first 2048 bytes of its 4096-byte fp32 row).
// ---------------------------------------------------------------------------
__global__ __launch_bounds__(256) void softmax_kernel(float* __restrict__ scores)
{
    const size_t row = blockIdx.x;
    float* p = scores + row * 1024;
    const int tid = threadIdx.x;
    float4 v = ((const float4*)p)[tid];

    float m = fmaxf(fmaxf(v.x, v.y), fmaxf(v.z, v.w));
    #pragma unroll
    for (int off = 32; off; off >>= 1) m = fmaxf(m, __shfl_down(m, off));
    __shared__ float red[4];
    const int w = tid >> 6;
    if ((tid & 63) == 0) red[w] = m;
    __syncthreads();
    const float M = fmaxf(fmaxf(red[0], red[1]), fmaxf(red[2], red[3]));

    float e0 = __expf(v.x - M), e1 = __expf(v.y - M);
    float e2 = __expf(v.z - M), e3 = __expf(v.w - M);
    float s = e0 + e1 + e2 + e3;
    #pragma unroll
    for (int off = 32; off; off >>= 1) s += __shfl_down(s, off);
    __syncthreads();
    if ((tid & 63) == 0) red[w] = s;
    __syncthreads();   // all reads of v are long done -> safe to overwrite row
    const float inv = 1.0f / (red[0] + red[1] + red[2] + red[3]);

    union { u16 u[4]; uint2 v2; } o;
    o.u[0] = f2bf(e0 * inv); o.u[1] = f2bf(e1 * inv);
    o.u[2] = f2bf(e2 * inv); o.u[3] = f2bf(e3 * inv);
    ((uint2*)p)[tid] = o.v2;
}

// ---------------------------------------------------------------------------
// Generic NT GEMM: C[m][n] = sum_k A[m][k] * B[n][k]   (both k-contiguous)
// 128x128 tile, BK=32, 256 threads (4 waves, each 64x64 of 16x16x32 MFMAs).
// MODE 0: qkv   -> q,k bf16 [B,T,C]; v bf16 [B,C,T]; + bias[n]
// MODE 1: score -> fp32 [B,T,S] * scale
// MODE 2: pv    -> bf16 [B,T,C]
// MODE 3: proj  -> fp32 d_out[B,C,T] = acc + bias[n] + x[b][n][m]
// ---------------------------------------------------------------------------
template <int MODE>
__global__ __launch_bounds__(256) void gemm_nt(
    const u16* __restrict__ A, const u16* __restrict__ B,
    size_t strideA, size_t strideB, int lda, int ldb, int K,
    u16* __restrict__ o0, u16* __restrict__ o1, u16* __restrict__ o2,
    float* __restrict__ fo, const float* __restrict__ bias,
    const float* __restrict__ xres, float scale)
{
    __shared__ u16 As[128 * 32];
    __shared__ u16 Bs[128 * 32];

    const int tid  = threadIdx.x;
    const int lane = tid & 63;
    const int wave = tid >> 6;
    const int wm   = (wave >> 1) * 64;
    const int wn   = (wave & 1) * 64;
    const int lrow = lane & 15;
    const int lq8  = (lane >> 4) * 8;
    const int b    = blockIdx.z;

    const u16* Ab = A + (size_t)b * strideA + (size_t)blockIdx.y * 128 * lda;
    const u16* Bb = B + (size_t)b * strideB + (size_t)blockIdx.x * 128 * ldb;

    const int sr = tid >> 2;        // staging row 0..63
    const int sc = (tid & 3) * 8;   // staging col (elements)

    f32x4 acc[4][4] = {};

    for (int k0 = 0; k0 < K; k0 += 32) {
        __syncthreads();
        GLDS16(Ab + (size_t)sr * lda + k0 + sc,        As + tid * 8);
        GLDS16(Ab + (size_t)(sr + 64) * lda + k0 + sc, As + 2048 + tid * 8);
        GLDS16(Bb + (size_t)sr * ldb + k0 + sc,        Bs + tid * 8);
        GLDS16(Bb + (size_t)(sr + 64) * ldb + k0 + sc, Bs + 2048 + tid * 8);
        __syncthreads();

        bf16x8 af[4], bfr[4];
        #pragma unroll
        for (int i = 0; i < 4; i++)
            af[i] = *(const bf16x8*)(As + (wm + i * 16 + lrow) * 32 + lq8);
        #pragma unroll
        for (int j = 0; j < 4; j++)
            bfr[j] = *(const bf16x8*)(Bs + (wn + j * 16 + lrow) * 32 + lq8);
        #pragma unroll
        for (int i = 0; i < 4; i++)
            #pragma unroll
            for (int j = 0; j < 4; j++)
                acc[i][j] = __builtin_amdgcn_mfma_f32_16x16x32_bf16(
                    af[i], bfr[j], acc[i][j], 0, 0, 0);
    }

    const int m0 = blockIdx.y * 128 + wm + (lane >> 4) * 4;  // + i*16 + r
    const int n0 = blockIdx.x * 128 + wn + lrow;             // + j*16

    #pragma unroll
    for (int i = 0; i < 4; i++) {
        #pragma unroll
        for (int j = 0; j < 4; j++) {
            const int n = n0 + j * 16;
            if (MODE == 0) {
                const float bv = bias[n];
                #pragma unroll
                for (int r = 0; r < 4; r++) {
                    const int m = m0 + i * 16 + r;
                    const u16 h = f2bf(acc[i][j][r] + bv);
                    if (n < 512)
                        o0[((size_t)b * 1024 + m) * 512 + n] = h;
                    else if (n < 1024)
                        o1[((size_t)b * 1024 + m) * 512 + (n - 512)] = h;
                    else
                        o2[((size_t)b * 512 + (n - 1024)) * 1024 + m] = h;
                }
            } else if (MODE == 1) {
                #pragma unroll
                for (int r = 0; r < 4; r++) {
                    const int m = m0 + i * 16 + r;
                    fo[((size_t)b * 1024 + m) * 1024 + n] = acc[i][j][r] * scale;
                }
            } else if (MODE == 2) {
                #pragma unroll
                for (int r = 0; r < 4; r++) {
                    const int m = m0 + i * 16 + r;
                    o0[((size_t)b * 1024 + m) * 512 + n] = f2bf(acc[i][j][r]);
                }
            } else {  // MODE 3: proj + bias + residual, out [B,C,T] fp32
                const float bv = bias[n];
                const int m = m0 + i * 16;
                const size_t off = ((size_t)b * 512 + n) * 1024 + m;
                const float4 xv = *(const float4*)(xres + off);
                float4 ov;
                ov.x = acc[i][j][0] + bv + xv.x;
                ov.y = acc[i][j][1] + bv + xv.y;
                ov.z = acc[i][j][2] + bv + xv.z;
                ov.w = acc[i][j][3] + bv + xv.w;
                *(float4*)(fo + off) = ov;
            }
        }
    }
}

// ---------------------------------------------------------------------------
extern "C" void kernel_launch(void* const* d_in, const int* in_sizes, int n_in,
                              void* d_out, int out_size, void* d_ws, size_t ws_size,
                              hipStream_t stream)
{
    const float* x     = (const float*)d_in[0];
    const float* gamma = (const float*)d_in[1];
    const float* beta  = (const float*)d_in[2];
    const float* Wq    = (const float*)d_in[3];
    const float* bq    = (const float*)d_in[4];
    const float* Wk    = (const float*)d_in[5];
    const float* bk    = (const float*)d_in[6];
    const float* Wv    = (const float*)d_in[7];
    const float* bv    = (const float*)d_in[8];
    const float* Wp    = (const float*)d_in[9];
    const float* bp    = (const float*)d_in[10];

    char* ws = (char*)d_ws;
    u16*   Wqkv   = (u16*)(ws + 0);           // 1,572,864 B
    u16*   Wpb    = (u16*)(ws + 1572864);     //   524,288 B
    float* bqkv   = (float*)(ws + 2097152);   //     8,192 B
    u16*   ht     = (u16*)(ws + 2105344);     // 16,777,216 B  (reused as h2)
    u16*   kt     = (u16*)(ws + 18882560);    // 16,777,216 B
    u16*   vv     = (u16*)(ws + 35659776);    // 16,777,216 B
    float* scores = (float*)(ws + 52436992);  // 67,108,864 B (P bf16 in-place)
    // total ws: 119,545,856 B
    u16*   qt  = (u16*)d_out;   // scratch: q [B,T,C] bf16 (16.8MB of 33.5MB)
    u16*   h2  = ht;
    float* out = (float*)d_out;

    convert_kernel<<<4096, 256, 0, stream>>>(Wq, Wk, Wv, Wp, bq, bk, bv,
                                             Wqkv, Wpb, bqkv);
    gn_kernel<<<dim3(32, 16), 256, 0, stream>>>(x, gamma, beta, ht);

    // GEMM1 qkv: M=1024(T) N=1536(3C) K=512 ; A=ht[B,T,C], B=Wqkv[3C,C]
    gemm_nt<0><<<dim3(12, 8, 16), 256, 0, stream>>>(
        ht, Wqkv, 524288, 0, 512, 512, 512,
        qt, kt, vv, nullptr, bqkv, nullptr, 0.f);

    // GEMM2 scores: M=1024(T) N=1024(S) K=512 ; A=qt, B=kt ; *C^-0.5
    gemm_nt<1><<<dim3(8, 8, 16), 256, 0, stream>>>(
        qt, kt, 524288, 524288, 512, 512, 512,
        nullptr, nullptr, nullptr, scores, nullptr, nullptr,
        0.044194173824159216f);

    softmax_kernel<<<16384, 256, 0, stream>>>(scores);

    // GEMM3 pv: M=1024(T) N=512(C) K=1024(S) ; A=P (lda 2048, in-place), B=v[C,S]
    gemm_nt<2><<<dim3(4, 8, 16), 256, 0, stream>>>(
        (const u16*)scores, vv, 2097152, 524288, 2048, 1024, 1024,
        h2, nullptr, nullptr, nullptr, nullptr, nullptr, 0.f);

    // GEMM4 proj+residual: M=1024(T) N=512(Cout) K=512 ; A=h2, B=Wp[Cout,Cin]
    gemm_nt<3><<<dim3(4, 8, 16), 256, 0, stream>>>(
        h2, Wpb, 524288, 0, 512, 512, 512,
        nullptr, nullptr, nullptr, out, bp, x, 0.f);
}

// Round 2
// 264.079 us; speedup vs baseline: 1.1269x; 1.1269x over previous
//
#include <hip/hip_runtime.h>

typedef unsigned short u16;
typedef __bf16 bf16x8 __attribute__((ext_vector_type(8)));
typedef float f32x4 __attribute__((ext_vector_type(4)));

__device__ __forceinline__ u16 f2bf(float f) {
    unsigned u = __builtin_bit_cast(unsigned, f);
    u += 0x7fffu + ((u >> 16) & 1u);
    return (u16)(u >> 16);
}

#define GLDS16(g, l) __builtin_amdgcn_global_load_lds( \
    (const __attribute__((address_space(1))) void*)(g), \
    (__attribute__((address_space(3))) void*)(l), 16, 0, 0)

// ---------------------------------------------------------------------------
// Weight conversion: fp32 -> bf16 (Wq|Wk|Wv stacked, Wp), concat biases.
// ---------------------------------------------------------------------------
__global__ __launch_bounds__(256) void convert_kernel(
    const float* __restrict__ Wq, const float* __restrict__ Wk,
    const float* __restrict__ Wv, const float* __restrict__ Wp,
    const float* __restrict__ bq, const float* __restrict__ bk,
    const float* __restrict__ bv,
    u16* __restrict__ Wqkv, u16* __restrict__ Wpb, float* __restrict__ bqkv)
{
    int idx = blockIdx.x * 256 + threadIdx.x;  // 4096 blocks * 256 = 1048576
    if (idx < 786432) {
        int which = idx >> 18;            // 262144 elems per matrix
        int off   = idx & 262143;
        const float* src = (which == 0) ? Wq : (which == 1) ? Wk : Wv;
        Wqkv[idx] = f2bf(src[off]);
    } else {
        int off = idx - 786432;
        Wpb[off] = f2bf(Wp[off]);
    }
    if (idx < 1536) {
        const float* bsrc = (idx < 512) ? bq : (idx < 1024) ? bk : bv;
        bqkv[idx] = bsrc[idx & 511];
    }
}

// ---------------------------------------------------------------------------
// GroupNorm: x [B,C,T] fp32 -> h_t [B,T,C] bf16.  One block per (b, group).
// ---------------------------------------------------------------------------
__global__ __launch_bounds__(256) void gn_kernel(
    const float* __restrict__ x, const float* __restrict__ gamma,
    const float* __restrict__ beta, u16* __restrict__ ht)
{
    const int g = blockIdx.x, b = blockIdx.y, tid = threadIdx.x;
    const float* xg = x + ((size_t)b * 512 + (size_t)g * 16) * 1024;

    float s = 0.f, s2 = 0.f;
    const float4* x4 = (const float4*)xg;
    #pragma unroll 4
    for (int i = tid; i < 4096; i += 256) {
        float4 v = x4[i];
        s  += v.x + v.y + v.z + v.w;
        s2 += v.x * v.x + v.y * v.y + v.z * v.z + v.w * v.w;
    }
    #pragma unroll
    for (int off = 32; off; off >>= 1) {
        s  += __shfl_down(s, off);
        s2 += __shfl_down(s2, off);
    }
    __shared__ float rs[4], rs2[4];
    __shared__ float stat[2];
    const int w = tid >> 6;
    if ((tid & 63) == 0) { rs[w] = s; rs2[w] = s2; }
    __syncthreads();
    if (tid == 0) {
        float S  = rs[0] + rs[1] + rs[2] + rs[3];
        float S2 = rs2[0] + rs2[1] + rs2[2] + rs2[3];
        float mean = S * (1.f / 16384.f);
        float var  = S2 * (1.f / 16384.f) - mean * mean;
        stat[0] = mean;
        stat[1] = rsqrtf(var + 1e-5f);
    }
    __syncthreads();
    const float mean = stat[0], rstd = stat[1];

    float ga[16], be[16];
    #pragma unroll
    for (int ci = 0; ci < 16; ci++) {
        ga[ci] = gamma[g * 16 + ci];
        be[ci] = beta[g * 16 + ci];
    }
    for (int t = tid; t < 1024; t += 256) {
        u16 yv[16];
        #pragma unroll
        for (int ci = 0; ci < 16; ci++) {
            float v = xg[ci * 1024 + t];
            yv[ci] = f2bf((v - mean) * rstd * ga[ci] + be[ci]);
        }
        uint4* dst = (uint4*)(ht + ((size_t)b * 1024 + t) * 512 + g * 16);
        dst[0] = ((const uint4*)yv)[0];
        dst[1] = ((const uint4*)yv)[1];
    }
}

// ---------------------------------------------------------------------------
// Row softmax over scores [16*1024 rows, 1024 cols] fp32, writes bf16 P
// IN PLACE (row r bf16 occupies first 2048 bytes of its 4096-byte fp32 row).
// ---------------------------------------------------------------------------
__global__ __launch_bounds__(256) void softmax_kernel(float* __restrict__ scores)
{
    const size_t row = blockIdx.x;
    float* p = scores + row * 1024;
    const int tid = threadIdx.x;
    float4 v = ((const float4*)p)[tid];

    float m = fmaxf(fmaxf(v.x, v.y), fmaxf(v.z, v.w));
    #pragma unroll
    for (int off = 32; off; off >>= 1) m = fmaxf(m, __shfl_down(m, off));
    __shared__ float red[4];
    const int w = tid >> 6;
    if ((tid & 63) == 0) red[w] = m;
    __syncthreads();
    const float M = fmaxf(fmaxf(red[0], red[1]), fmaxf(red[2], red[3]));

    float e0 = __expf(v.x - M), e1 = __expf(v.y - M);
    float e2 = __expf(v.z - M), e3 = __expf(v.w - M);
    float s = e0 + e1 + e2 + e3;
    #pragma unroll
    for (int off = 32; off; off >>= 1) s += __shfl_down(s, off);
    __syncthreads();
    if ((tid & 63) == 0) red[w] = s;
    __syncthreads();
    const float inv = 1.0f / (red[0] + red[1] + red[2] + red[3]);

    union { u16 u[4]; uint2 v2; } o;
    o.u[0] = f2bf(e0 * inv); o.u[1] = f2bf(e1 * inv);
    o.u[2] = f2bf(e2 * inv); o.u[3] = f2bf(e3 * inv);
    ((uint2*)p)[tid] = o.v2;
}

// ---------------------------------------------------------------------------
// Generic NT GEMM: C[m][n] = sum_k A[m][k] * B[n][k]   (both k-contiguous)
// 128x128 tile, BK=64, 256 threads (4 waves, each 64x64 of 16x16x32 MFMAs).
// XOR chunk swizzle: LDS slot (r, c) holds global chunk c ^ (r&7); fragment
// reads fetch chunk q from slot q ^ (r&7)  -> max 2-way bank aliasing (free).
// MODE 0: qkv   -> q,k bf16 [B,T,C]; v bf16 [B,C,T] (ushort4); + bias[n]
// MODE 1: score -> fp32 scores[t=n][s=m] * scale  (float4 stores)
// MODE 2: pv    -> bf16 h2[t=n][c=m]              (ushort4 stores)
// MODE 3: proj  -> fp32 d_out[B,C,T] = acc + bias[n] + x  (float4)
// ---------------------------------------------------------------------------
template <int MODE>
__global__ __launch_bounds__(256) void gemm_nt(
    const u16* __restrict__ A, const u16* __restrict__ B,
    size_t strideA, size_t strideB, int lda, int ldb, int K,
    u16* __restrict__ o0, u16* __restrict__ o1, u16* __restrict__ o2,
    float* __restrict__ fo, const float* __restrict__ bias,
    const float* __restrict__ xres, float scale)
{
    __shared__ u16 As[128 * 64];
    __shared__ u16 Bs[128 * 64];

    const int tid  = threadIdx.x;
    const int lane = tid & 63;
    const int wave = tid >> 6;
    const int wm   = (wave >> 1) * 64;
    const int wn   = (wave & 1) * 64;
    const int lrow = lane & 15;
    const int quad = lane >> 4;           // 0..3
    const int b    = blockIdx.z;

    const u16* Ab = A + (size_t)b * strideA + (size_t)blockIdx.y * 128 * lda;
    const u16* Bb = B + (size_t)b * strideB + (size_t)blockIdx.x * 128 * ldb;

    // staging: per wave, 4 GLDS instrs each for As/Bs; 8 rows x 8 chunks per instr
    const int srow = lane >> 3;           // row within 8-row slab (== r & 7)
    const int sc   = lane & 7;            // LDS chunk slot 0..7
    const int scg  = sc ^ srow;           // global chunk to fetch (swizzle)

    f32x4 acc[4][4] = {};

    for (int k0 = 0; k0 < K; k0 += 64) {
        __syncthreads();
        #pragma unroll
        for (int s = 0; s < 4; s++) {
            const int r = wave * 32 + s * 8 + srow;
            GLDS16(Ab + (size_t)r * lda + k0 + scg * 8, As + r * 64 + sc * 8);
            GLDS16(Bb + (size_t)r * ldb + k0 + scg * 8, Bs + r * 64 + sc * 8);
        }
        __syncthreads();

        #pragma unroll
        for (int ks = 0; ks < 2; ks++) {
            bf16x8 af[4], bfr[4];
            #pragma unroll
            for (int i = 0; i < 4; i++) {
                const int r = wm + i * 16 + lrow;
                af[i] = *(const bf16x8*)(As + r * 64 + (((ks * 4 + quad) ^ (r & 7)) * 8));
            }
            #pragma unroll
            for (int j = 0; j < 4; j++) {
                const int r = wn + j * 16 + lrow;
                bfr[j] = *(const bf16x8*)(Bs + r * 64 + (((ks * 4 + quad) ^ (r & 7)) * 8));
            }
            #pragma unroll
            for (int i = 0; i < 4; i++)
                #pragma unroll
                for (int j = 0; j < 4; j++)
                    acc[i][j] = __builtin_amdgcn_mfma_f32_16x16x32_bf16(
                        af[i], bfr[j], acc[i][j], 0, 0, 0);
        }
    }

    const int m0 = blockIdx.y * 128 + wm + quad * 4;   // + i*16 (+ r)
    const int n0 = blockIdx.x * 128 + wn + lrow;       // + j*16

    #pragma unroll
    for (int i = 0; i < 4; i++) {
        #pragma unroll
        for (int j = 0; j < 4; j++) {
            const int n = n0 + j * 16;
            if (MODE == 0) {
                const float bv = bias[n];
                if (n < 1024) {  // q or k: [B,T,C], scalar (m-strided)
                    u16* dst = (n < 512) ? o0 : o1;
                    const int nn = n & 511;
                    #pragma unroll
                    for (int r = 0; r < 4; r++) {
                        const int m = m0 + i * 16 + r;
                        dst[((size_t)b * 1024 + m) * 512 + nn] =
                            f2bf(acc[i][j][r] + bv);
                    }
                } else {         // v: [B,C,T], m-contiguous -> ushort4
                    ushort4 hv;
                    hv.x = f2bf(acc[i][j][0] + bv);
                    hv.y = f2bf(acc[i][j][1] + bv);
                    hv.z = f2bf(acc[i][j][2] + bv);
                    hv.w = f2bf(acc[i][j][3] + bv);
                    *(ushort4*)(o2 + ((size_t)b * 512 + (n - 1024)) * 1024 +
                                m0 + i * 16) = hv;
                }
            } else if (MODE == 1) {   // scores[t=n][s=m], float4
                float4 ov;
                ov.x = acc[i][j][0] * scale;
                ov.y = acc[i][j][1] * scale;
                ov.z = acc[i][j][2] * scale;
                ov.w = acc[i][j][3] * scale;
                *(float4*)(fo + ((size_t)b * 1024 + n) * 1024 + m0 + i * 16) = ov;
            } else if (MODE == 2) {   // h2[t=n][c=m], ushort4
                ushort4 hv;
                hv.x = f2bf(acc[i][j][0]);
                hv.y = f2bf(acc[i][j][1]);
                hv.z = f2bf(acc[i][j][2]);
                hv.w = f2bf(acc[i][j][3]);
                *(ushort4*)(o0 + ((size_t)b * 1024 + n) * 512 + m0 + i * 16) = hv;
            } else {                  // MODE 3: proj + bias + residual, [B,C,T]
                const float bv = bias[n];
                const size_t off = ((size_t)b * 512 + n) * 1024 + m0 + i * 16;
                const float4 xv = *(const float4*)(xres + off);
                float4 ov;
                ov.x = acc[i][j][0] + bv + xv.x;
                ov.y = acc[i][j][1] + bv + xv.y;
                ov.z = acc[i][j][2] + bv + xv.z;
                ov.w = acc[i][j][3] + bv + xv.w;
                *(float4*)(fo + off) = ov;
            }
        }
    }
}

// ---------------------------------------------------------------------------
extern "C" void kernel_launch(void* const* d_in, const int* in_sizes, int n_in,
                              void* d_out, int out_size, void* d_ws, size_t ws_size,
                              hipStream_t stream)
{
    const float* x     = (const float*)d_in[0];
    const float* gamma = (const float*)d_in[1];
    const float* beta  = (const float*)d_in[2];
    const float* Wq    = (const float*)d_in[3];
    const float* bq    = (const float*)d_in[4];
    const float* Wk    = (const float*)d_in[5];
    const float* bk    = (const float*)d_in[6];
    const float* Wv    = (const float*)d_in[7];
    const float* bv    = (const float*)d_in[8];
    const float* Wp    = (const float*)d_in[9];
    const float* bp    = (const float*)d_in[10];

    char* ws = (char*)d_ws;
    u16*   Wqkv   = (u16*)(ws + 0);           // 1,572,864 B
    u16*   Wpb    = (u16*)(ws + 1572864);     //   524,288 B
    float* bqkv   = (float*)(ws + 2097152);   //     8,192 B
    u16*   ht     = (u16*)(ws + 2105344);     // 16,777,216 B  (reused as h2)
    u16*   kt     = (u16*)(ws + 18882560);    // 16,777,216 B
    u16*   vv     = (u16*)(ws + 35659776);    // 16,777,216 B
    float* scores = (float*)(ws + 52436992);  // 67,108,864 B (P bf16 in-place)
    u16*   qt  = (u16*)d_out;   // scratch: q [B,T,C] bf16 (16.8MB of 33.5MB)
    u16*   h2  = ht;
    float* out = (float*)d_out;

    convert_kernel<<<4096, 256, 0, stream>>>(Wq, Wk, Wv, Wp, bq, bk, bv,
                                             Wqkv, Wpb, bqkv);
    gn_kernel<<<dim3(32, 16), 256, 0, stream>>>(x, gamma, beta, ht);

    // GEMM1 qkv: M=1024(T) N=1536(3C) K=512 ; A=ht[B,T,C], B=Wqkv[3C,C]
    gemm_nt<0><<<dim3(12, 8, 16), 256, 0, stream>>>(
        ht, Wqkv, 524288, 0, 512, 512, 512,
        qt, kt, vv, nullptr, bqkv, nullptr, 0.f);

    // GEMM2 scores: M=1024(S) N=1024(T) K=512 ; A=kt, B=qt ; *C^-0.5
    gemm_nt<1><<<dim3(8, 8, 16), 256, 0, stream>>>(
        kt, qt, 524288, 524288, 512, 512, 512,
        nullptr, nullptr, nullptr, scores, nullptr, nullptr,
        0.044194173824159216f);

    softmax_kernel<<<16384, 256, 0, stream>>>(scores);

    // GEMM3 pv: M=512(C) N=1024(T) K=1024(S) ; A=v[C,S], B=P[T,S] (ldb 2048)
    gemm_nt<2><<<dim3(8, 4, 16), 256, 0, stream>>>(
        vv, (const u16*)scores, 524288, 2097152, 1024, 2048, 1024,
        h2, nullptr, nullptr, nullptr, nullptr, nullptr, 0.f);

    // GEMM4 proj+residual: M=1024(T) N=512(Cout) K=512 ; A=h2, B=Wp[Cout,Cin]
    gemm_nt<3><<<dim3(4, 8, 16), 256, 0, stream>>>(
        h2, Wpb, 524288, 0, 512, 512, 512,
        nullptr, nullptr, nullptr, out, bp, x, 0.f);
}

// Round 3
// 258.003 us; speedup vs baseline: 1.1535x; 1.0236x over previous
//
#include <hip/hip_runtime.h>

typedef unsigned short u16;
typedef __bf16 bf16x8 __attribute__((ext_vector_type(8)));
typedef float f32x16 __attribute__((ext_vector_type(16)));

__device__ __forceinline__ u16 f2bf(float f) {
    unsigned u = __builtin_bit_cast(unsigned, f);
    u += 0x7fffu + ((u >> 16) & 1u);
    return (u16)(u >> 16);
}
__device__ __forceinline__ float bf2f(u16 h) {
    return __builtin_bit_cast(float, (unsigned)h << 16);
}

#define GLDS16(g, l) __builtin_amdgcn_global_load_lds( \
    (const __attribute__((address_space(1))) void*)(g), \
    (__attribute__((address_space(3))) void*)(l), 16, 0, 0)

#define QK_SCALE 0.044194173824159216f

// ---------------------------------------------------------------------------
// Weight conversion: fp32 -> bf16 (Wq|Wk|Wv stacked, Wp), concat biases.
// Wq and bq are pre-scaled by C^-1/2 so GEMM2 output is the scaled scores.
// ---------------------------------------------------------------------------
__global__ __launch_bounds__(256) void convert_kernel(
    const float* __restrict__ Wq, const float* __restrict__ Wk,
    const float* __restrict__ Wv, const float* __restrict__ Wp,
    const float* __restrict__ bq, const float* __restrict__ bk,
    const float* __restrict__ bv,
    u16* __restrict__ Wqkv, u16* __restrict__ Wpb, float* __restrict__ bqkv)
{
    int idx = blockIdx.x * 256 + threadIdx.x;  // 4096 blocks * 256 = 1048576
    if (idx < 786432) {
        int which = idx >> 18;            // 262144 elems per matrix
        int off   = idx & 262143;
        if (which == 0)
            Wqkv[idx] = f2bf(Wq[off] * QK_SCALE);
        else
            Wqkv[idx] = f2bf(((which == 1) ? Wk : Wv)[off]);
    } else {
        int off = idx - 786432;
        Wpb[off] = f2bf(Wp[off]);
    }
    if (idx < 1536) {
        float bvv = (idx < 512) ? bq[idx] * QK_SCALE
                  : (idx < 1024) ? bk[idx & 511] : bv[idx & 511];
        bqkv[idx] = bvv;
    }
}

// ---------------------------------------------------------------------------
// GroupNorm: x [B,C,T] fp32 -> h_t [B,T,C] bf16.  One block per (b, group).
// ---------------------------------------------------------------------------
__global__ __launch_bounds__(256) void gn_kernel(
    const float* __restrict__ x, const float* __restrict__ gamma,
    const float* __restrict__ beta, u16* __restrict__ ht)
{
    const int g = blockIdx.x, b = blockIdx.y, tid = threadIdx.x;
    const float* xg = x + ((size_t)b * 512 + (size_t)g * 16) * 1024;

    float s = 0.f, s2 = 0.f;
    const float4* x4 = (const float4*)xg;
    #pragma unroll 4
    for (int i = tid; i < 4096; i += 256) {
        float4 v = x4[i];
        s  += v.x + v.y + v.z + v.w;
        s2 += v.x * v.x + v.y * v.y + v.z * v.z + v.w * v.w;
    }
    #pragma unroll
    for (int off = 32; off; off >>= 1) {
        s  += __shfl_down(s, off);
        s2 += __shfl_down(s2, off);
    }
    __shared__ float rs[4], rs2[4];
    __shared__ float stat[2];
    const int w = tid >> 6;
    if ((tid & 63) == 0) { rs[w] = s; rs2[w] = s2; }
    __syncthreads();
    if (tid == 0) {
        float S  = rs[0] + rs[1] + rs[2] + rs[3];
        float S2 = rs2[0] + rs2[1] + rs2[2] + rs2[3];
        float mean = S * (1.f / 16384.f);
        float var  = S2 * (1.f / 16384.f) - mean * mean;
        stat[0] = mean;
        stat[1] = rsqrtf(var + 1e-5f);
    }
    __syncthreads();
    const float mean = stat[0], rstd = stat[1];

    float ga[16], be[16];
    #pragma unroll
    for (int ci = 0; ci < 16; ci++) {
        ga[ci] = gamma[g * 16 + ci];
        be[ci] = beta[g * 16 + ci];
    }
    for (int t = tid; t < 1024; t += 256) {
        u16 yv[16];
        #pragma unroll
        for (int ci = 0; ci < 16; ci++) {
            float v = xg[ci * 1024 + t];
            yv[ci] = f2bf((v - mean) * rstd * ga[ci] + be[ci]);
        }
        uint4* dst = (uint4*)(ht + ((size_t)b * 1024 + t) * 512 + g * 16);
        dst[0] = ((const uint4*)yv)[0];
        dst[1] = ((const uint4*)yv)[1];
    }
}

// ---------------------------------------------------------------------------
// Row softmax over bf16 scores [16384 rows, 1024 cols], in place.
// One wave per row, 16 elems per lane, butterfly reductions, no LDS.
// ---------------------------------------------------------------------------
__global__ __launch_bounds__(256) void softmax_kernel(u16* __restrict__ scores)
{
    const int row  = blockIdx.x * 4 + (threadIdx.x >> 6);
    const int lane = threadIdx.x & 63;
    u16* p = scores + (size_t)row * 1024 + lane * 16;

    uint4 w0 = ((const uint4*)p)[0];
    uint4 w1 = ((const uint4*)p)[1];
    unsigned wd[8] = {w0.x, w0.y, w0.z, w0.w, w1.x, w1.y, w1.z, w1.w};
    float v[16];
    #pragma unroll
    for (int i = 0; i < 8; i++) {
        v[2 * i]     = __builtin_bit_cast(float, wd[i] << 16);
        v[2 * i + 1] = __builtin_bit_cast(float, wd[i] & 0xffff0000u);
    }
    float m = v[0];
    #pragma unroll
    for (int i = 1; i < 16; i++) m = fmaxf(m, v[i]);
    #pragma unroll
    for (int off = 1; off < 64; off <<= 1) m = fmaxf(m, __shfl_xor(m, off));

    float s = 0.f;
    #pragma unroll
    for (int i = 0; i < 16; i++) { v[i] = __expf(v[i] - m); s += v[i]; }
    #pragma unroll
    for (int off = 1; off < 64; off <<= 1) s += __shfl_xor(s, off);
    const float inv = 1.0f / s;

    #pragma unroll
    for (int i = 0; i < 8; i++) {
        unsigned lo = f2bf(v[2 * i] * inv);
        unsigned hi = f2bf(v[2 * i + 1] * inv);
        wd[i] = lo | (hi << 16);
    }
    ((uint4*)p)[0] = make_uint4(wd[0], wd[1], wd[2], wd[3]);
    ((uint4*)p)[1] = make_uint4(wd[4], wd[5], wd[6], wd[7]);
}

// ---------------------------------------------------------------------------
// Generic NT GEMM: C[m][n] = sum_k A[m][k] * B[n][k]   (both k-contiguous)
// 128x128 tile, BK=64, 256 threads; 4 waves (2x2 of 64x64), each wave 2x2
// frags of 32x32x16 MFMA.  XOR chunk swizzle on LDS (GLDS-compatible).
// C/D layout (m101): col=lane&31, row=(reg&3)+8*(reg>>2)+4*(lane>>5).
// MODE 0: qkv   -> q,k bf16 [B,T,C] scalar; v bf16 [B,C,T] ushort4; +bias[n]
// MODE 1: score -> bf16 scores[b][t=n][s=m]          (ushort4, scale folded)
// MODE 2: pv    -> bf16 h2[b][t=n][c=m]              (ushort4)
// MODE 3: proj  -> fp32 d_out[B,C,T] = acc + bias[n] + x  (float4)
// ---------------------------------------------------------------------------
template <int MODE>
__global__ __launch_bounds__(256) void gemm_nt(
    const u16* __restrict__ A, const u16* __restrict__ B,
    size_t strideA, size_t strideB, int lda, int ldb, int K,
    u16* __restrict__ o0, u16* __restrict__ o1, u16* __restrict__ o2,
    float* __restrict__ fo, const float* __restrict__ bias,
    const float* __restrict__ xres)
{
    __shared__ u16 As[128 * 64];
    __shared__ u16 Bs[128 * 64];

    const int tid   = threadIdx.x;
    const int lane  = tid & 63;
    const int wave  = tid >> 6;
    const int wm    = (wave >> 1) * 64;
    const int wn    = (wave & 1) * 64;
    const int l31   = lane & 31;
    const int khalf = lane >> 5;          // 0,1
    const int b     = blockIdx.z;

    const u16* Ab = A + (size_t)b * strideA + (size_t)blockIdx.y * 128 * lda;
    const u16* Bb = B + (size_t)b * strideB + (size_t)blockIdx.x * 128 * ldb;

    // staging: per wave, 4 GLDS instrs each for As/Bs; 8 rows x 8 chunks per instr
    const int srow = lane >> 3;           // row within 8-row slab (== r & 7)
    const int sc   = lane & 7;            // LDS chunk slot 0..7
    const int scg  = sc ^ srow;           // global chunk to fetch (swizzle)

    f32x16 acc[2][2] = {};

    for (int k0 = 0; k0 < K; k0 += 64) {
        __syncthreads();
        #pragma unroll
        for (int s = 0; s < 4; s++) {
            const int r = wave * 32 + s * 8 + srow;
            GLDS16(Ab + (size_t)r * lda + k0 + scg * 8, As + r * 64 + sc * 8);
            GLDS16(Bb + (size_t)r * ldb + k0 + scg * 8, Bs + r * 64 + sc * 8);
        }
        __syncthreads();

        #pragma unroll
        for (int ks = 0; ks < 4; ks++) {
            const int cidx = ks * 2 + khalf;      // k-chunk this half-wave reads
            const int slot = (cidx ^ (lane & 7)) * 8;
            bf16x8 af[2], bfr[2];
            #pragma unroll
            for (int i = 0; i < 2; i++)
                af[i] = *(const bf16x8*)(As + (wm + i * 32 + l31) * 64 + slot);
            #pragma unroll
            for (int j = 0; j < 2; j++)
                bfr[j] = *(const bf16x8*)(Bs + (wn + j * 32 + l31) * 64 + slot);
            #pragma unroll
            for (int i = 0; i < 2; i++)
                #pragma unroll
                for (int j = 0; j < 2; j++)
                    acc[i][j] = __builtin_amdgcn_mfma_f32_32x32x16_bf16(
                        af[i], bfr[j], acc[i][j], 0, 0, 0);
        }
    }

    // epilogue: rows come in 4 groups of 4 consecutive m per frag
    const int m_base = blockIdx.y * 128 + wm + 4 * khalf;  // + i*32 + 8*g (+r)
    const int n_base = blockIdx.x * 128 + wn + l31;        // + j*32

    #pragma unroll
    for (int i = 0; i < 2; i++) {
        #pragma unroll
        for (int j = 0; j < 2; j++) {
            const int n = n_base + j * 32;
            float bv = 0.f;
            if (MODE == 0 || MODE == 3) bv = bias[n];
            #pragma unroll
            for (int g = 0; g < 4; g++) {
                const int m = m_base + i * 32 + 8 * g;
                const float a0 = acc[i][j][4 * g]     + bv;
                const float a1 = acc[i][j][4 * g + 1] + bv;
                const float a2 = acc[i][j][4 * g + 2] + bv;
                const float a3 = acc[i][j][4 * g + 3] + bv;
                if (MODE == 0) {
                    if (n < 1024) {          // q or k: [B,T,C], scalar stores
                        u16* dst = (n < 512) ? o0 : o1;
                        const int nn = n & 511;
                        dst[((size_t)b * 1024 + m) * 512 + nn]     = f2bf(a0);
                        dst[((size_t)b * 1024 + m + 1) * 512 + nn] = f2bf(a1);
                        dst[((size_t)b * 1024 + m + 2) * 512 + nn] = f2bf(a2);
                        dst[((size_t)b * 1024 + m + 3) * 512 + nn] = f2bf(a3);
                    } else {                 // v: [B,C,T], ushort4
                        ushort4 hv = {f2bf(a0), f2bf(a1), f2bf(a2), f2bf(a3)};
                        *(ushort4*)(o2 + ((size_t)b * 512 + (n - 1024)) * 1024 + m) = hv;
                    }
                } else if (MODE == 1) {      // scores[b][t=n][s=m] bf16
                    ushort4 hv = {f2bf(a0), f2bf(a1), f2bf(a2), f2bf(a3)};
                    *(ushort4*)(o0 + ((size_t)b * 1024 + n) * 1024 + m) = hv;
                } else if (MODE == 2) {      // h2[b][t=n][c=m] bf16
                    ushort4 hv = {f2bf(a0), f2bf(a1), f2bf(a2), f2bf(a3)};
                    *(ushort4*)(o0 + ((size_t)b * 1024 + n) * 512 + m) = hv;
                } else {                     // proj + bias + residual, [B,C,T]
                    const size_t off = ((size_t)b * 512 + n) * 1024 + m;
                    const float4 xv = *(const float4*)(xres + off);
                    float4 ov = {a0 + xv.x, a1 + xv.y, a2 + xv.z, a3 + xv.w};
                    *(float4*)(fo + off) = ov;
                }
            }
        }
    }
}

// ---------------------------------------------------------------------------
extern "C" void kernel_launch(void* const* d_in, const int* in_sizes, int n_in,
                              void* d_out, int out_size, void* d_ws, size_t ws_size,
                              hipStream_t stream)
{
    const float* x     = (const float*)d_in[0];
    const float* gamma = (const float*)d_in[1];
    const float* beta  = (const float*)d_in[2];
    const float* Wq    = (const float*)d_in[3];
    const float* bq    = (const float*)d_in[4];
    const float* Wk    = (const float*)d_in[5];
    const float* bk    = (const float*)d_in[6];
    const float* Wv    = (const float*)d_in[7];
    const float* bv    = (const float*)d_in[8];
    const float* Wp    = (const float*)d_in[9];
    const float* bp    = (const float*)d_in[10];

    char* ws = (char*)d_ws;
    u16*   Wqkv   = (u16*)(ws + 0);           //  1,572,864 B
    u16*   Wpb    = (u16*)(ws + 1572864);     //    524,288 B
    float* bqkv   = (float*)(ws + 2097152);   //      8,192 B
    u16*   ht     = (u16*)(ws + 2105344);     // 16,777,216 B (reused as h2)
    u16*   kt     = (u16*)(ws + 18882560);    // 16,777,216 B
    u16*   vv     = (u16*)(ws + 35659776);    // 16,777,216 B
    u16*   scores = (u16*)(ws + 52436992);    // 33,554,432 B bf16 (P in place)
    // total ws: 85,991,424 B
    u16*   qt  = (u16*)d_out;   // scratch: q [B,T,C] bf16 (16.8MB of 33.5MB)
    u16*   h2  = ht;
    float* out = (float*)d_out;

    convert_kernel<<<4096, 256, 0, stream>>>(Wq, Wk, Wv, Wp, bq, bk, bv,
                                             Wqkv, Wpb, bqkv);
    gn_kernel<<<dim3(32, 16), 256, 0, stream>>>(x, gamma, beta, ht);

    // GEMM1 qkv: M=1024(T) N=1536(3C) K=512 ; A=ht[B,T,C], B=Wqkv[3C,C]
    gemm_nt<0><<<dim3(12, 8, 16), 256, 0, stream>>>(
        ht, Wqkv, 524288, 0, 512, 512, 512,
        qt, kt, vv, nullptr, bqkv, nullptr);

    // GEMM2 scores: M=1024(S) N=1024(T) K=512 ; A=kt, B=qt (scale pre-folded)
    gemm_nt<1><<<dim3(8, 8, 16), 256, 0, stream>>>(
        kt, qt, 524288, 524288, 512, 512, 512,
        scores, nullptr, nullptr, nullptr, nullptr, nullptr);

    softmax_kernel<<<4096, 256, 0, stream>>>(scores);

    // GEMM3 pv: M=512(C) N=1024(T) K=1024(S) ; A=v[C,S], B=P[T,S] compact
    gemm_nt<2><<<dim3(8, 4, 16), 256, 0, stream>>>(
        vv, scores, 524288, 1048576, 1024, 1024, 1024,
        h2, nullptr, nullptr, nullptr, nullptr, nullptr);

    // GEMM4 proj+residual: M=1024(T) N=512(Cout) K=512 ; A=h2, B=Wp[Cout,Cin]
    gemm_nt<3><<<dim3(4, 8, 16), 256, 0, stream>>>(
        h2, Wpb, 524288, 0, 512, 512, 512,
        nullptr, nullptr, nullptr, out, bp, x);
}